// Round 2
// baseline (557.005 us; speedup 1.0000x reference)
//
#include <hip/hip_runtime.h>
#include <hip/hip_bf16.h>

// Child-Sum Tree-LSTM: N=8192 nodes, K=8 children, D_IN=512, H=512, fp32 in/out.
// bf16 MFMA for GEMM work; fp32 elementwise epilogues; in-register child reduce.

#define NN 8192
#define KCH 8
#define HH 512

typedef __attribute__((ext_vector_type(4))) float f32x4;
typedef __attribute__((ext_vector_type(8))) short short8;

__device__ inline unsigned short f2bf(float f) {
    union { float f; unsigned u; } v; v.f = f;
    unsigned r = v.u + 0x7FFFu + ((v.u >> 16) & 1u);
    return (unsigned short)(r >> 16);
}
__device__ inline float bf2f(unsigned short b) {
    union { unsigned u; float f; } v; v.u = ((unsigned)b) << 16;
    return v.f;
}
__device__ inline float sigm(float x) { return 1.f / (1.f + __expf(-x)); }
__device__ inline float tanh_pf(float x) { return 2.f / (1.f + __expf(-2.f * x)) - 1.f; }

// async global->LDS, 16B per lane. LDS dest must be wave-uniform base.
__device__ __forceinline__ void gl16(const unsigned short* gsrc, unsigned short* ldst) {
    __builtin_amdgcn_global_load_lds(
        (const __attribute__((address_space(1))) unsigned int*)gsrc,
        (__attribute__((address_space(3))) unsigned int*)ldst,
        16, 0, 0);
}

// ---------------- prep kernels ----------------

__global__ void k_cvt(const float* __restrict__ in, unsigned short* __restrict__ outp) {
    int i = blockIdx.x * blockDim.x + threadIdx.x;
    float4 a = ((const float4*)in)[2 * i];
    float4 b = ((const float4*)in)[2 * i + 1];
    uint4 o;
    o.x = (unsigned)f2bf(a.x) | ((unsigned)f2bf(a.y) << 16);
    o.y = (unsigned)f2bf(a.z) | ((unsigned)f2bf(a.w) << 16);
    o.z = (unsigned)f2bf(b.x) | ((unsigned)f2bf(b.y) << 16);
    o.w = (unsigned)f2bf(b.z) | ((unsigned)f2bf(b.w) << 16);
    ((uint4*)outp)[i] = o;
}

__global__ void k_hsum(const float* __restrict__ ch, unsigned short* __restrict__ hs) {
    int i = blockIdx.x * blockDim.x + threadIdx.x;   // n*128 + h4
    int n = i >> 7, h4 = i & 127;
    const float4* base = (const float4*)(ch + (size_t)n * KCH * HH) + h4;
    float4 s = base[0];
#pragma unroll
    for (int k = 1; k < KCH; ++k) {
        float4 v = base[(size_t)k * 128];
        s.x += v.x; s.y += v.y; s.z += v.z; s.w += v.w;
    }
    unsigned long long pk = (unsigned long long)f2bf(s.x)
        | ((unsigned long long)f2bf(s.y) << 16)
        | ((unsigned long long)f2bf(s.z) << 32)
        | ((unsigned long long)f2bf(s.w) << 48);
    *(unsigned long long*)&hs[(size_t)i * 4] = pk;
}

// transpose 512x512 fp32 weight -> bf16 WT[c][k] = W[k][c]
struct P8 { const float* p[8]; };
__global__ void k_transpose_w(P8 wsrc, unsigned short* __restrict__ out) {
    __shared__ float tile[32][33];
    const float* W = wsrc.p[blockIdx.z];
    unsigned short* O = out + (size_t)blockIdx.z * 262144;
    int k0 = blockIdx.x * 32, c0 = blockIdx.y * 32;
    for (int r = threadIdx.y; r < 32; r += 8)
        tile[r][threadIdx.x] = W[(size_t)(k0 + r) * 512 + c0 + threadIdx.x];
    __syncthreads();
    for (int r = threadIdx.y; r < 32; r += 8)
        O[(size_t)(c0 + r) * 512 + k0 + threadIdx.x] = f2bf(tile[threadIdx.x][r]);
}

// ---------------- gates kernel: i,o,u activations + x@Wf ----------------
// BM=128, BN=64, BK=32, 256 threads = 4 waves (2x2), wave tile 64x32.
// Panel order in wT: [Wi,Wf,Wo,Wu, Ui,Uo,Uu, Uf]
__global__ __launch_bounds__(256) void k_gates(
    const unsigned short* __restrict__ xb,
    const unsigned short* __restrict__ hsb,
    const unsigned short* __restrict__ wT,
    const float* __restrict__ bWi, const float* __restrict__ bUi,
    const float* __restrict__ bWf,
    const float* __restrict__ bWo, const float* __restrict__ bUo,
    const float* __restrict__ bWu, const float* __restrict__ bUu,
    unsigned short* __restrict__ Pq,   // i*u (bf16)
    unsigned short* __restrict__ Oq,   // sigmoid(o) (bf16)
    unsigned short* __restrict__ Fq)   // x@Wf + bWf (bf16)
{
    __shared__ unsigned short a_lds[128][32];
    __shared__ unsigned short b_lds[4][64][32];
    const int t = threadIdx.x, lane = t & 63, wid = t >> 6;
    const int wr = wid >> 1, wc = wid & 1;
    const int r0 = blockIdx.y * 128, c0 = blockIdx.x * 64;

    f32x4 acc_i[4][2] = {}; f32x4 acc_f[4][2] = {};
    f32x4 acc_o[4][2] = {}; f32x4 acc_u[4][2] = {};

    const int koff = (lane >> 4) * 8;
    const int arow = wr * 64 + (lane & 15);
    const int bcol = wc * 32 + (lane & 15);
    const int rsub = lane >> 2, c8 = (lane & 3) * 8;

#pragma unroll 1
    for (int phase = 0; phase < 2; ++phase) {
        const unsigned short* Asrc = phase ? hsb : xb;
        const unsigned short* Bbase = wT + (size_t)(phase ? 4 : 0) * 262144;
        const int nchunk = phase ? 20 : 24;   // 8 A-chunks + 4*npanel B-chunks
#pragma unroll 1
        for (int kq = 0; kq < 512; kq += 32) {
            __syncthreads();
            for (int c = wid; c < nchunk; c += 4) {
                if (c < 8) {
                    gl16(&Asrc[(size_t)(r0 + c * 16 + rsub) * 512 + kq + c8],
                         &a_lds[c * 16][0]);
                } else {
                    int d = c - 8, p = d >> 2, cb = d & 3;
                    gl16(&Bbase[(size_t)p * 262144 + (size_t)(c0 + cb * 16 + rsub) * 512 + kq + c8],
                         &b_lds[p][cb * 16][0]);
                }
            }
            __syncthreads();
            short8 af[4];
#pragma unroll
            for (int m = 0; m < 4; ++m) af[m] = *(const short8*)&a_lds[arow + m * 16][koff];
#pragma unroll
            for (int p = 0; p < 4; ++p) {
                if (phase && p == 3) break;
                short8 b0 = *(const short8*)&b_lds[p][bcol][koff];
                short8 b1 = *(const short8*)&b_lds[p][bcol + 16][koff];
                f32x4 (*acc)[2] = (phase == 0)
                    ? (p == 0 ? acc_i : p == 1 ? acc_f : p == 2 ? acc_o : acc_u)
                    : (p == 0 ? acc_i : p == 1 ? acc_o : acc_u);
#pragma unroll
                for (int m = 0; m < 4; ++m) {
                    acc[m][0] = __builtin_amdgcn_mfma_f32_16x16x32_bf16(af[m], b0, acc[m][0], 0, 0, 0);
                    acc[m][1] = __builtin_amdgcn_mfma_f32_16x16x32_bf16(af[m], b1, acc[m][1], 0, 0, 0);
                }
            }
        }
    }
    // epilogue
#pragma unroll
    for (int m = 0; m < 4; ++m) {
#pragma unroll
        for (int n = 0; n < 2; ++n) {
            int col = c0 + wc * 32 + n * 16 + (lane & 15);
            float bi = bWi[col] + bUi[col];
            float bf = bWf[col];
            float bo = bWo[col] + bUo[col];
            float bu = bWu[col] + bUu[col];
#pragma unroll
            for (int r = 0; r < 4; ++r) {
                int row = r0 + wr * 64 + m * 16 + (lane >> 4) * 4 + r;
                size_t idx = (size_t)row * 512 + col;
                float vi = sigm(acc_i[m][n][r] + bi);
                float vu = tanh_pf(acc_u[m][n][r] + bu);
                Pq[idx] = f2bf(vi * vu);
                Oq[idx] = f2bf(sigm(acc_o[m][n][r] + bo));
                Fq[idx] = f2bf(acc_f[m][n][r] + bf);
            }
        }
    }
}

// ---------------- f-einsum + combine kernel ----------------
// BM=64 child rows (8 nodes), BN=512 (full width -> child_h read ONCE).
// 512 threads = 8 waves (1x8), wave tile 64x64. In-register child reduce.
__global__ __launch_bounds__(512, 2) void k_fc(
    const float* __restrict__ ch,            // child_h [65536][512] fp32
    const float* __restrict__ cc,            // child_c
    const unsigned short* __restrict__ ufT,  // Uf^T bf16 [512][512]
    const float* __restrict__ bUf,
    const unsigned short* __restrict__ Pq,
    const unsigned short* __restrict__ Oq,
    const unsigned short* __restrict__ Fq,
    float* __restrict__ out)                 // [2][8192][512]
{
    __shared__ unsigned short a_lds[64][32];    // 4 KB
    __shared__ unsigned short b_lds[512][32];   // 32 KB
    const int t = threadIdx.x, lane = t & 63, wid = t >> 6;
    const int wc = wid;
    const int r0c = blockIdx.x * 64;            // child-row base

    f32x4 acc[4][4] = {};
    const int koff = (lane >> 4) * 8;
    const int rsub = lane >> 2, cb8 = (lane & 3) * 8;
    // A staging (fp32 -> bf16 convert): thread t handles row t>>3, cols (t&7)*4..+3
    const int sarow = t >> 3, sac4 = (t & 7) * 4;

#pragma unroll 1
    for (int kq = 0; kq < 512; kq += 32) {
        __syncthreads();
        {   // stage A: 64x32 fp32 -> bf16
            float4 v = *(const float4*)&ch[(size_t)(r0c + sarow) * 512 + kq + sac4];
            unsigned long long pk = (unsigned long long)f2bf(v.x)
                | ((unsigned long long)f2bf(v.y) << 16)
                | ((unsigned long long)f2bf(v.z) << 32)
                | ((unsigned long long)f2bf(v.w) << 48);
            *(unsigned long long*)&a_lds[sarow][sac4] = pk;
        }
        // stage B: all 512 Uf^T rows, k-slice kq (32 chunks of 1KB, 4/wave)
        for (int c = wid; c < 32; c += 8)
            gl16(&ufT[(size_t)(c * 16 + rsub) * 512 + kq + cb8], &b_lds[c * 16][0]);
        __syncthreads();
        short8 af[4], bfr[4];
#pragma unroll
        for (int m = 0; m < 4; ++m) af[m] = *(const short8*)&a_lds[m * 16 + (lane & 15)][koff];
#pragma unroll
        for (int n = 0; n < 4; ++n) bfr[n] = *(const short8*)&b_lds[wc * 64 + n * 16 + (lane & 15)][koff];
#pragma unroll
        for (int m = 0; m < 4; ++m)
#pragma unroll
            for (int n = 0; n < 4; ++n)
                acc[m][n] = __builtin_amdgcn_mfma_f32_16x16x32_bf16(af[m], bfr[n], acc[m][n], 0, 0, 0);
    }

    // epilogue: in-register per-node reduce over 8 children
    const int g = lane >> 4;
    float bUfv[4];
#pragma unroll
    for (int n = 0; n < 4; ++n) bUfv[n] = bUf[wc * 64 + n * 16 + (lane & 15)];

#pragma unroll
    for (int m = 0; m < 4; ++m) {
        int node = (r0c >> 3) + 2 * m + (g >> 1);
#pragma unroll
        for (int n = 0; n < 4; ++n) {
            int col = wc * 64 + n * 16 + (lane & 15);
            size_t nidx = (size_t)node * 512 + col;
            float xf = bf2f(Fq[nidx]) + bUfv[n];
            float fcs = 0.f;
#pragma unroll
            for (int r = 0; r < 4; ++r) {
                int R = r0c + m * 16 + g * 4 + r;
                float pre = acc[m][n][r] + xf;
                fcs += sigm(pre) * cc[(size_t)R * 512 + col];
            }
            fcs += __shfl_xor(fcs, 16);
            if ((g & 1) == 0) {   // lanes g=0 (node 2m), g=2 (node 2m+1) write
                float cv = bf2f(Pq[nidx]) + fcs;
                out[nidx] = bf2f(Oq[nidx]) * tanh_pf(cv);
                out[(size_t)NN * HH + nidx] = cv;
            }
        }
    }
}

// ---------------- launch ----------------
extern "C" void kernel_launch(void* const* d_in, const int* in_sizes, int n_in,
                              void* d_out, int out_size, void* d_ws, size_t ws_size,
                              hipStream_t stream) {
    const float* x   = (const float*)d_in[0];
    const float* ch  = (const float*)d_in[1];
    const float* cc  = (const float*)d_in[2];
    const float* Wi  = (const float*)d_in[3];  const float* bWi = (const float*)d_in[4];
    const float* Ui  = (const float*)d_in[5];  const float* bUi = (const float*)d_in[6];
    const float* Wf  = (const float*)d_in[7];  const float* bWf = (const float*)d_in[8];
    const float* Uf  = (const float*)d_in[9];  const float* bUf = (const float*)d_in[10];
    const float* Wo  = (const float*)d_in[11]; const float* bWo = (const float*)d_in[12];
    const float* Uo  = (const float*)d_in[13]; const float* bUo = (const float*)d_in[14];
    const float* Wu  = (const float*)d_in[15]; const float* bWu = (const float*)d_in[16];
    const float* Uu  = (const float*)d_in[17]; const float* bUu = (const float*)d_in[18];
    float* out = (float*)d_out;

    unsigned short* xb  = (unsigned short*)d_ws;                 // 8192*512
    unsigned short* hsb = xb  + (size_t)NN * HH;                 // 8192*512
    unsigned short* wT  = hsb + (size_t)NN * HH;                 // 8*512*512
    unsigned short* Pq  = wT  + (size_t)8 * 262144;
    unsigned short* Oq  = Pq  + (size_t)NN * HH;
    unsigned short* Fq  = Oq  + (size_t)NN * HH;

    k_cvt<<<(NN * HH / 8) / 256, 256, 0, stream>>>(x, xb);
    k_hsum<<<(NN * 128) / 256, 256, 0, stream>>>(ch, hsb);
    P8 wp;  // order: Wi,Wf,Wo,Wu, Ui,Uo,Uu, Uf
    wp.p[0] = Wi; wp.p[1] = Wf; wp.p[2] = Wo; wp.p[3] = Wu;
    wp.p[4] = Ui; wp.p[5] = Uo; wp.p[6] = Uu; wp.p[7] = Uf;
    k_transpose_w<<<dim3(16, 16, 8), dim3(32, 8), 0, stream>>>(wp, wT);
    k_gates<<<dim3(8, 64), 256, 0, stream>>>(xb, hsb, wT,
                                             bWi, bUi, bWf, bWo, bUo, bWu, bUu,
                                             Pq, Oq, Fq);
    k_fc<<<dim3(1024), 512, 0, stream>>>(ch, cc, wT + (size_t)7 * 262144, bUf,
                                         Pq, Oq, Fq, out);
}

// Round 3
// 215.996 us; speedup vs baseline: 2.5788x; 2.5788x over previous
//
#include <hip/hip_runtime.h>
#include <hip/hip_bf16.h>

// Child-Sum Tree-LSTM: N=8192 nodes, K=8 children, D_IN=512, H=512, fp32 in/out.
// bf16 MFMA for GEMM work; fp32 elementwise epilogues; in-register child reduce.

#define NN 8192
#define KCH 8
#define HH 512

typedef __attribute__((ext_vector_type(4))) float f32x4;
typedef __attribute__((ext_vector_type(8))) short short8;

__device__ inline unsigned short f2bf(float f) {
    union { float f; unsigned u; } v; v.f = f;
    unsigned r = v.u + 0x7FFFu + ((v.u >> 16) & 1u);
    return (unsigned short)(r >> 16);
}
__device__ inline float bf2f(unsigned short b) {
    union { unsigned u; float f; } v; v.u = ((unsigned)b) << 16;
    return v.f;
}
__device__ inline float sigm(float x) { return 1.f / (1.f + __expf(-x)); }
__device__ inline float tanh_pf(float x) { return 2.f / (1.f + __expf(-2.f * x)) - 1.f; }

// async global->LDS, 16B per lane. LDS dest must be wave-uniform base.
__device__ __forceinline__ void gl16(const unsigned short* gsrc, unsigned short* ldst) {
    __builtin_amdgcn_global_load_lds(
        (const __attribute__((address_space(1))) unsigned int*)gsrc,
        (__attribute__((address_space(3))) unsigned int*)ldst,
        16, 0, 0);
}

// ---------------- prep kernels ----------------

__global__ void k_cvt(const float* __restrict__ in, unsigned short* __restrict__ outp) {
    int i = blockIdx.x * blockDim.x + threadIdx.x;
    float4 a = ((const float4*)in)[2 * i];
    float4 b = ((const float4*)in)[2 * i + 1];
    uint4 o;
    o.x = (unsigned)f2bf(a.x) | ((unsigned)f2bf(a.y) << 16);
    o.y = (unsigned)f2bf(a.z) | ((unsigned)f2bf(a.w) << 16);
    o.z = (unsigned)f2bf(b.x) | ((unsigned)f2bf(b.y) << 16);
    o.w = (unsigned)f2bf(b.z) | ((unsigned)f2bf(b.w) << 16);
    ((uint4*)outp)[i] = o;
}

__global__ void k_hsum(const float* __restrict__ ch, unsigned short* __restrict__ hs) {
    int i = blockIdx.x * blockDim.x + threadIdx.x;   // n*128 + h4
    int n = i >> 7, h4 = i & 127;
    const float4* base = (const float4*)(ch + (size_t)n * KCH * HH) + h4;
    float4 s = base[0];
#pragma unroll
    for (int k = 1; k < KCH; ++k) {
        float4 v = base[(size_t)k * 128];
        s.x += v.x; s.y += v.y; s.z += v.z; s.w += v.w;
    }
    unsigned long long pk = (unsigned long long)f2bf(s.x)
        | ((unsigned long long)f2bf(s.y) << 16)
        | ((unsigned long long)f2bf(s.z) << 32)
        | ((unsigned long long)f2bf(s.w) << 48);
    *(unsigned long long*)&hs[(size_t)i * 4] = pk;
}

// transpose 512x512 fp32 weight -> bf16 WT[c][k] = W[k][c]
struct P8 { const float* p[8]; };
__global__ void k_transpose_w(P8 wsrc, unsigned short* __restrict__ out) {
    __shared__ float tile[32][33];
    const float* W = wsrc.p[blockIdx.z];
    unsigned short* O = out + (size_t)blockIdx.z * 262144;
    int k0 = blockIdx.x * 32, c0 = blockIdx.y * 32;
    for (int r = threadIdx.y; r < 32; r += 8)
        tile[r][threadIdx.x] = W[(size_t)(k0 + r) * 512 + c0 + threadIdx.x];
    __syncthreads();
    for (int r = threadIdx.y; r < 32; r += 8)
        O[(size_t)(c0 + r) * 512 + k0 + threadIdx.x] = f2bf(tile[threadIdx.x][r]);
}

// ---------------- GEMM helper (compile-time acc binding!) ----------------
__device__ __forceinline__ void gate_mfma(f32x4 (&acc)[4][2], const short8 (&af)[4],
                                          const unsigned short (*bl)[32], int bcol, int koff) {
    short8 b0 = *(const short8*)&bl[bcol][koff];
    short8 b1 = *(const short8*)&bl[bcol + 16][koff];
#pragma unroll
    for (int m = 0; m < 4; ++m) {
        acc[m][0] = __builtin_amdgcn_mfma_f32_16x16x32_bf16(af[m], b0, acc[m][0], 0, 0, 0);
        acc[m][1] = __builtin_amdgcn_mfma_f32_16x16x32_bf16(af[m], b1, acc[m][1], 0, 0, 0);
    }
}

// ---------------- gates kernel: i,o,u activations + x@Wf ----------------
// BM=128, BN=64, BK=32, 256 threads = 4 waves (2x2), wave tile 64x32.
// Panel order in wT: [Wi,Wf,Wo,Wu, Ui,Uo,Uu, Uf]. 1D grid of 512, XCD-swizzled.
__global__ __launch_bounds__(256) void k_gates(
    const unsigned short* __restrict__ xb,
    const unsigned short* __restrict__ hsb,
    const unsigned short* __restrict__ wT,
    const float* __restrict__ bWi, const float* __restrict__ bUi,
    const float* __restrict__ bWf,
    const float* __restrict__ bWo, const float* __restrict__ bUo,
    const float* __restrict__ bWu, const float* __restrict__ bUu,
    unsigned short* __restrict__ Pq,   // i*u (bf16)
    unsigned short* __restrict__ Oq,   // sigmoid(o) (bf16)
    unsigned short* __restrict__ Fq)   // x@Wf + bWf (bf16)
{
    __shared__ unsigned short a_lds[128][32];
    __shared__ unsigned short b_lds[4][64][32];
    const int t = threadIdx.x, lane = t & 63, wid = t >> 6;
    const int wr = wid >> 1, wc = wid & 1;
    // XCD swizzle: each XCD owns 8 complete row-panels (A fetched once/XCD,
    // weights L2-resident per XCD). nwg=512, 512%8==0 -> bijective.
    const int nid = (blockIdx.x & 7) * 64 + (blockIdx.x >> 3);
    const int r0 = (nid >> 3) * 128, c0 = (nid & 7) * 64;

    f32x4 acc_i[4][2] = {}; f32x4 acc_f[4][2] = {};
    f32x4 acc_o[4][2] = {}; f32x4 acc_u[4][2] = {};

    const int koff = (lane >> 4) * 8;
    const int arow = wr * 64 + (lane & 15);
    const int bcol = wc * 32 + (lane & 15);
    const int rsub = lane >> 2, c8 = (lane & 3) * 8;

    // ---- phase 0: x @ {Wi, Wf, Wo, Wu} ----
#pragma unroll 1
    for (int kq = 0; kq < 512; kq += 32) {
        __syncthreads();
        for (int c = wid; c < 24; c += 4) {
            if (c < 8) {
                gl16(&xb[(size_t)(r0 + c * 16 + rsub) * 512 + kq + c8], &a_lds[c * 16][0]);
            } else {
                int d = c - 8, p = d >> 2, cb = d & 3;
                gl16(&wT[(size_t)p * 262144 + (size_t)(c0 + cb * 16 + rsub) * 512 + kq + c8],
                     &b_lds[p][cb * 16][0]);
            }
        }
        __syncthreads();
        short8 af[4];
#pragma unroll
        for (int m = 0; m < 4; ++m) af[m] = *(const short8*)&a_lds[arow + m * 16][koff];
        gate_mfma(acc_i, af, b_lds[0], bcol, koff);
        gate_mfma(acc_f, af, b_lds[1], bcol, koff);
        gate_mfma(acc_o, af, b_lds[2], bcol, koff);
        gate_mfma(acc_u, af, b_lds[3], bcol, koff);
    }
    // ---- phase 1: h_sum @ {Ui, Uo, Uu} ----
#pragma unroll 1
    for (int kq = 0; kq < 512; kq += 32) {
        __syncthreads();
        for (int c = wid; c < 20; c += 4) {
            if (c < 8) {
                gl16(&hsb[(size_t)(r0 + c * 16 + rsub) * 512 + kq + c8], &a_lds[c * 16][0]);
            } else {
                int d = c - 8, p = d >> 2, cb = d & 3;
                gl16(&wT[(size_t)(4 + p) * 262144 + (size_t)(c0 + cb * 16 + rsub) * 512 + kq + c8],
                     &b_lds[p][cb * 16][0]);
            }
        }
        __syncthreads();
        short8 af[4];
#pragma unroll
        for (int m = 0; m < 4; ++m) af[m] = *(const short8*)&a_lds[arow + m * 16][koff];
        gate_mfma(acc_i, af, b_lds[0], bcol, koff);
        gate_mfma(acc_o, af, b_lds[1], bcol, koff);
        gate_mfma(acc_u, af, b_lds[2], bcol, koff);
    }
    // epilogue
#pragma unroll
    for (int m = 0; m < 4; ++m) {
#pragma unroll
        for (int n = 0; n < 2; ++n) {
            int col = c0 + wc * 32 + n * 16 + (lane & 15);
            float bi = bWi[col] + bUi[col];
            float bf = bWf[col];
            float bo = bWo[col] + bUo[col];
            float bu = bWu[col] + bUu[col];
#pragma unroll
            for (int r = 0; r < 4; ++r) {
                int row = r0 + wr * 64 + m * 16 + (lane >> 4) * 4 + r;
                size_t idx = (size_t)row * 512 + col;
                float vi = sigm(acc_i[m][n][r] + bi);
                float vu = tanh_pf(acc_u[m][n][r] + bu);
                Pq[idx] = f2bf(vi * vu);
                Oq[idx] = f2bf(sigm(acc_o[m][n][r] + bo));
                Fq[idx] = f2bf(acc_f[m][n][r] + bf);
            }
        }
    }
}

// ---------------- f-einsum + combine kernel ----------------
// BM=64 child rows (8 nodes), BN=512 (full width -> child_h read ONCE).
// 512 threads = 8 waves (1x8), wave tile 64x64. In-register child reduce.
__global__ __launch_bounds__(512, 2) void k_fc(
    const float* __restrict__ ch,            // child_h [65536][512] fp32
    const float* __restrict__ cc,            // child_c
    const unsigned short* __restrict__ ufT,  // Uf^T bf16 [512][512]
    const float* __restrict__ bUf,
    const unsigned short* __restrict__ Pq,
    const unsigned short* __restrict__ Oq,
    const unsigned short* __restrict__ Fq,
    float* __restrict__ out)                 // [2][8192][512]
{
    __shared__ unsigned short a_lds[64][32];    // 4 KB
    __shared__ unsigned short b_lds[512][32];   // 32 KB
    const int t = threadIdx.x, lane = t & 63, wid = t >> 6;
    const int wc = wid;
    const int r0c = blockIdx.x * 64;            // child-row base

    f32x4 acc[4][4] = {};
    const int koff = (lane >> 4) * 8;
    const int rsub = lane >> 2, cb8 = (lane & 3) * 8;
    const int sarow = t >> 3, sac4 = (t & 7) * 4;

#pragma unroll 1
    for (int kq = 0; kq < 512; kq += 32) {
        __syncthreads();
        {   // stage A: 64x32 fp32 -> bf16
            float4 v = *(const float4*)&ch[(size_t)(r0c + sarow) * 512 + kq + sac4];
            unsigned long long pk = (unsigned long long)f2bf(v.x)
                | ((unsigned long long)f2bf(v.y) << 16)
                | ((unsigned long long)f2bf(v.z) << 32)
                | ((unsigned long long)f2bf(v.w) << 48);
            *(unsigned long long*)&a_lds[sarow][sac4] = pk;
        }
        // stage B: all 512 Uf^T rows, k-slice kq (32 chunks of 1KB, 4/wave)
        for (int c = wid; c < 32; c += 8)
            gl16(&ufT[(size_t)(c * 16 + rsub) * 512 + kq + cb8], &b_lds[c * 16][0]);
        __syncthreads();
        short8 af[4], bfr[4];
#pragma unroll
        for (int m = 0; m < 4; ++m) af[m] = *(const short8*)&a_lds[m * 16 + (lane & 15)][koff];
#pragma unroll
        for (int n = 0; n < 4; ++n) bfr[n] = *(const short8*)&b_lds[wc * 64 + n * 16 + (lane & 15)][koff];
#pragma unroll
        for (int m = 0; m < 4; ++m)
#pragma unroll
            for (int n = 0; n < 4; ++n)
                acc[m][n] = __builtin_amdgcn_mfma_f32_16x16x32_bf16(af[m], bfr[n], acc[m][n], 0, 0, 0);
    }

    // epilogue: in-register per-node reduce over 8 children
    const int g = lane >> 4;
    float bUfv[4];
#pragma unroll
    for (int n = 0; n < 4; ++n) bUfv[n] = bUf[wc * 64 + n * 16 + (lane & 15)];

#pragma unroll
    for (int m = 0; m < 4; ++m) {
        int node = (r0c >> 3) + 2 * m + (g >> 1);
#pragma unroll
        for (int n = 0; n < 4; ++n) {
            int col = wc * 64 + n * 16 + (lane & 15);
            size_t nidx = (size_t)node * 512 + col;
            float xf = bf2f(Fq[nidx]) + bUfv[n];
            float fcs = 0.f;
#pragma unroll
            for (int r = 0; r < 4; ++r) {
                int R = r0c + m * 16 + g * 4 + r;
                float pre = acc[m][n][r] + xf;
                fcs += sigm(pre) * cc[(size_t)R * 512 + col];
            }
            fcs += __shfl_xor(fcs, 16);
            if ((g & 1) == 0) {   // lanes g=0 (node 2m), g=2 (node 2m+1) write
                float cv = bf2f(Pq[nidx]) + fcs;
                out[nidx] = bf2f(Oq[nidx]) * tanh_pf(cv);
                out[(size_t)NN * HH + nidx] = cv;
            }
        }
    }
}

// ---------------- launch ----------------
extern "C" void kernel_launch(void* const* d_in, const int* in_sizes, int n_in,
                              void* d_out, int out_size, void* d_ws, size_t ws_size,
                              hipStream_t stream) {
    const float* x   = (const float*)d_in[0];
    const float* ch  = (const float*)d_in[1];
    const float* cc  = (const float*)d_in[2];
    const float* Wi  = (const float*)d_in[3];  const float* bWi = (const float*)d_in[4];
    const float* Ui  = (const float*)d_in[5];  const float* bUi = (const float*)d_in[6];
    const float* Wf  = (const float*)d_in[7];  const float* bWf = (const float*)d_in[8];
    const float* Uf  = (const float*)d_in[9];  const float* bUf = (const float*)d_in[10];
    const float* Wo  = (const float*)d_in[11]; const float* bWo = (const float*)d_in[12];
    const float* Uo  = (const float*)d_in[13]; const float* bUo = (const float*)d_in[14];
    const float* Wu  = (const float*)d_in[15]; const float* bWu = (const float*)d_in[16];
    const float* Uu  = (const float*)d_in[17]; const float* bUu = (const float*)d_in[18];
    float* out = (float*)d_out;

    unsigned short* xb  = (unsigned short*)d_ws;                 // 8192*512
    unsigned short* hsb = xb  + (size_t)NN * HH;                 // 8192*512
    unsigned short* wT  = hsb + (size_t)NN * HH;                 // 8*512*512
    unsigned short* Pq  = wT  + (size_t)8 * 262144;
    unsigned short* Oq  = Pq  + (size_t)NN * HH;
    unsigned short* Fq  = Oq  + (size_t)NN * HH;

    k_cvt<<<(NN * HH / 8) / 256, 256, 0, stream>>>(x, xb);
    k_hsum<<<(NN * 128) / 256, 256, 0, stream>>>(ch, hsb);
    P8 wp;  // order: Wi,Wf,Wo,Wu, Ui,Uo,Uu, Uf
    wp.p[0] = Wi; wp.p[1] = Wf; wp.p[2] = Wo; wp.p[3] = Wu;
    wp.p[4] = Ui; wp.p[5] = Uo; wp.p[6] = Uu; wp.p[7] = Uf;
    k_transpose_w<<<dim3(16, 16, 8), dim3(32, 8), 0, stream>>>(wp, wT);
    k_gates<<<dim3(512), 256, 0, stream>>>(xb, hsb, wT,
                                           bWi, bUi, bWf, bWo, bUo, bWu, bUu,
                                           Pq, Oq, Fq);
    k_fc<<<dim3(1024), 512, 0, stream>>>(ch, cc, wT + (size_t)7 * 262144, bUf,
                                         Pq, Oq, Fq, out);
}

// Round 4
// 211.969 us; speedup vs baseline: 2.6278x; 1.0190x over previous
//
#include <hip/hip_runtime.h>
#include <hip/hip_bf16.h>

// Child-Sum Tree-LSTM: N=8192 nodes, K=8 children, D_IN=512, H=512, fp32 in/out.
// bf16 MFMA; fragment-order LDS (conflict-free); double-buffered staging.

#define NN 8192
#define KCH 8
#define HH 512

typedef __attribute__((ext_vector_type(4))) float f32x4;
typedef __attribute__((ext_vector_type(8))) short short8;

__device__ inline unsigned short f2bf(float f) {
    union { float f; unsigned u; } v; v.f = f;
    unsigned r = v.u + 0x7FFFu + ((v.u >> 16) & 1u);
    return (unsigned short)(r >> 16);
}
__device__ inline float bf2f(unsigned short b) {
    union { unsigned u; float f; } v; v.u = ((unsigned)b) << 16;
    return v.f;
}
__device__ inline float sigm(float x) { return 1.f / (1.f + __expf(-x)); }
__device__ inline float tanh_pf(float x) { return 2.f / (1.f + __expf(-2.f * x)) - 1.f; }

// async global->LDS, 16B per lane. Per-lane global src, wave-uniform LDS dest;
// lane l's 16B lands at dst + l*16.
__device__ __forceinline__ void gl16(const unsigned short* gsrc, unsigned short* ldst) {
    __builtin_amdgcn_global_load_lds(
        (const __attribute__((address_space(1))) unsigned int*)gsrc,
        (__attribute__((address_space(3))) unsigned int*)ldst,
        16, 0, 0);
}

// ---------------- prep kernels ----------------

__global__ void k_cvt(const float* __restrict__ in, unsigned short* __restrict__ outp) {
    int i = blockIdx.x * blockDim.x + threadIdx.x;
    float4 a = ((const float4*)in)[2 * i];
    float4 b = ((const float4*)in)[2 * i + 1];
    uint4 o;
    o.x = (unsigned)f2bf(a.x) | ((unsigned)f2bf(a.y) << 16);
    o.y = (unsigned)f2bf(a.z) | ((unsigned)f2bf(a.w) << 16);
    o.z = (unsigned)f2bf(b.x) | ((unsigned)f2bf(b.y) << 16);
    o.w = (unsigned)f2bf(b.z) | ((unsigned)f2bf(b.w) << 16);
    ((uint4*)outp)[i] = o;
}

__global__ void k_hsum(const float* __restrict__ ch, unsigned short* __restrict__ hs) {
    int i = blockIdx.x * blockDim.x + threadIdx.x;   // n*128 + h4
    int n = i >> 7, h4 = i & 127;
    const float4* base = (const float4*)(ch + (size_t)n * KCH * HH) + h4;
    float4 s = base[0];
#pragma unroll
    for (int k = 1; k < KCH; ++k) {
        float4 v = base[(size_t)k * 128];
        s.x += v.x; s.y += v.y; s.z += v.z; s.w += v.w;
    }
    unsigned long long pk = (unsigned long long)f2bf(s.x)
        | ((unsigned long long)f2bf(s.y) << 16)
        | ((unsigned long long)f2bf(s.z) << 32)
        | ((unsigned long long)f2bf(s.w) << 48);
    *(unsigned long long*)&hs[(size_t)i * 4] = pk;
}

// transpose 512x512 fp32 weight -> bf16 WT[c][k] = W[k][c]
struct P8 { const float* p[8]; };
__global__ void k_transpose_w(P8 wsrc, unsigned short* __restrict__ out) {
    __shared__ float tile[32][33];
    const float* W = wsrc.p[blockIdx.z];
    unsigned short* O = out + (size_t)blockIdx.z * 262144;
    int k0 = blockIdx.x * 32, c0 = blockIdx.y * 32;
    for (int r = threadIdx.y; r < 32; r += 8)
        tile[r][threadIdx.x] = W[(size_t)(k0 + r) * 512 + c0 + threadIdx.x];
    __syncthreads();
    for (int r = threadIdx.y; r < 32; r += 8)
        O[(size_t)(c0 + r) * 512 + k0 + threadIdx.x] = f2bf(tile[threadIdx.x][r]);
}

// ---------------- gates kernel: i,o,u activations + x@Wf ----------------
// BM=128, BN=64, BK=32, 4 waves (2x2), wave tile 64x32. Double-buffered,
// fragment-order LDS. Panel order in wT: [Wi,Wf,Wo,Wu, Ui,Uo,Uu, Uf].
__global__ __launch_bounds__(256, 2) void k_gates(
    const unsigned short* __restrict__ xb,
    const unsigned short* __restrict__ hsb,
    const unsigned short* __restrict__ wT,
    const float* __restrict__ bWi, const float* __restrict__ bUi,
    const float* __restrict__ bWf,
    const float* __restrict__ bWo, const float* __restrict__ bUo,
    const float* __restrict__ bWu, const float* __restrict__ bUu,
    unsigned short* __restrict__ Pq,   // i*u (bf16)
    unsigned short* __restrict__ Oq,   // sigmoid(o) (bf16)
    unsigned short* __restrict__ Fq)   // x@Wf + bWf (bf16)
{
    // per buffer: A = 8 subtiles (4096 sh), B = 16 subtiles (8192 sh) -> 24KB
    __shared__ unsigned short lds[2][12288];
    const int t = threadIdx.x, lane = t & 63, wid = t >> 6;
    const int wr = wid >> 1, wc = wid & 1;
    // XCD swizzle (nwg=512, %8==0 -> bijective)
    const int nid = (blockIdx.x & 7) * 64 + (blockIdx.x >> 3);
    const int r0 = (nid >> 3) * 128, c0 = (nid & 7) * 64;

    f32x4 acc_i[4][2] = {}; f32x4 acc_f[4][2] = {};
    f32x4 acc_o[4][2] = {}; f32x4 acc_u[4][2] = {};

    const int frow = lane & 15, fk = (lane >> 4) * 8;

    auto stage0 = [&](unsigned short* buf, int kq) {
        for (int c = wid; c < 24; c += 4) {
            if (c < 8) {
                gl16(&xb[(size_t)(r0 + c * 16 + frow) * 512 + kq + fk], &buf[c * 512]);
            } else {
                int d = c - 8, p = d >> 2, cb = d & 3;
                gl16(&wT[(size_t)p * 262144 + (size_t)(c0 + cb * 16 + frow) * 512 + kq + fk],
                     &buf[4096 + d * 512]);
            }
        }
    };
    auto stage1 = [&](unsigned short* buf, int kq) {
        for (int c = wid; c < 20; c += 4) {
            if (c < 8) {
                gl16(&hsb[(size_t)(r0 + c * 16 + frow) * 512 + kq + fk], &buf[c * 512]);
            } else {
                int d = c - 8, p = d >> 2, cb = d & 3;
                gl16(&wT[(size_t)(4 + p) * 262144 + (size_t)(c0 + cb * 16 + frow) * 512 + kq + fk],
                     &buf[4096 + d * 512]);
            }
        }
    };

    stage0(lds[0], 0);

    // ---- phase 0: x @ {Wi, Wf, Wo, Wu} ----
#pragma unroll 1
    for (int kq = 0; kq < 512; kq += 32) {
        unsigned short* cur = lds[(kq >> 5) & 1];
        unsigned short* nxt = lds[((kq >> 5) & 1) ^ 1];
        __syncthreads();
        if (kq < 480) stage0(nxt, kq + 32); else stage1(nxt, 0);
        short8 af[4];
#pragma unroll
        for (int m = 0; m < 4; ++m) af[m] = *(const short8*)&cur[(wr * 4 + m) * 512 + lane * 8];
#pragma unroll
        for (int p = 0; p < 4; ++p) {
            short8 b0 = *(const short8*)&cur[4096 + (p * 4 + wc * 2 + 0) * 512 + lane * 8];
            short8 b1 = *(const short8*)&cur[4096 + (p * 4 + wc * 2 + 1) * 512 + lane * 8];
#pragma unroll
            for (int m = 0; m < 4; ++m) {
                if (p == 0) {
                    acc_i[m][0] = __builtin_amdgcn_mfma_f32_16x16x32_bf16(af[m], b0, acc_i[m][0], 0, 0, 0);
                    acc_i[m][1] = __builtin_amdgcn_mfma_f32_16x16x32_bf16(af[m], b1, acc_i[m][1], 0, 0, 0);
                } else if (p == 1) {
                    acc_f[m][0] = __builtin_amdgcn_mfma_f32_16x16x32_bf16(af[m], b0, acc_f[m][0], 0, 0, 0);
                    acc_f[m][1] = __builtin_amdgcn_mfma_f32_16x16x32_bf16(af[m], b1, acc_f[m][1], 0, 0, 0);
                } else if (p == 2) {
                    acc_o[m][0] = __builtin_amdgcn_mfma_f32_16x16x32_bf16(af[m], b0, acc_o[m][0], 0, 0, 0);
                    acc_o[m][1] = __builtin_amdgcn_mfma_f32_16x16x32_bf16(af[m], b1, acc_o[m][1], 0, 0, 0);
                } else {
                    acc_u[m][0] = __builtin_amdgcn_mfma_f32_16x16x32_bf16(af[m], b0, acc_u[m][0], 0, 0, 0);
                    acc_u[m][1] = __builtin_amdgcn_mfma_f32_16x16x32_bf16(af[m], b1, acc_u[m][1], 0, 0, 0);
                }
            }
        }
    }
    // ---- phase 1: h_sum @ {Ui, Uo, Uu} ----
#pragma unroll 1
    for (int kq = 0; kq < 512; kq += 32) {
        unsigned short* cur = lds[(kq >> 5) & 1];
        unsigned short* nxt = lds[((kq >> 5) & 1) ^ 1];
        __syncthreads();
        if (kq < 480) stage1(nxt, kq + 32);
        short8 af[4];
#pragma unroll
        for (int m = 0; m < 4; ++m) af[m] = *(const short8*)&cur[(wr * 4 + m) * 512 + lane * 8];
#pragma unroll
        for (int p = 0; p < 3; ++p) {
            short8 b0 = *(const short8*)&cur[4096 + (p * 4 + wc * 2 + 0) * 512 + lane * 8];
            short8 b1 = *(const short8*)&cur[4096 + (p * 4 + wc * 2 + 1) * 512 + lane * 8];
#pragma unroll
            for (int m = 0; m < 4; ++m) {
                if (p == 0) {
                    acc_i[m][0] = __builtin_amdgcn_mfma_f32_16x16x32_bf16(af[m], b0, acc_i[m][0], 0, 0, 0);
                    acc_i[m][1] = __builtin_amdgcn_mfma_f32_16x16x32_bf16(af[m], b1, acc_i[m][1], 0, 0, 0);
                } else if (p == 1) {
                    acc_o[m][0] = __builtin_amdgcn_mfma_f32_16x16x32_bf16(af[m], b0, acc_o[m][0], 0, 0, 0);
                    acc_o[m][1] = __builtin_amdgcn_mfma_f32_16x16x32_bf16(af[m], b1, acc_o[m][1], 0, 0, 0);
                } else {
                    acc_u[m][0] = __builtin_amdgcn_mfma_f32_16x16x32_bf16(af[m], b0, acc_u[m][0], 0, 0, 0);
                    acc_u[m][1] = __builtin_amdgcn_mfma_f32_16x16x32_bf16(af[m], b1, acc_u[m][1], 0, 0, 0);
                }
            }
        }
    }
    // epilogue
#pragma unroll
    for (int m = 0; m < 4; ++m) {
#pragma unroll
        for (int n = 0; n < 2; ++n) {
            int col = c0 + wc * 32 + n * 16 + (lane & 15);
            float bi = bWi[col] + bUi[col];
            float bf = bWf[col];
            float bo = bWo[col] + bUo[col];
            float bu = bWu[col] + bUu[col];
#pragma unroll
            for (int r = 0; r < 4; ++r) {
                int row = r0 + wr * 64 + m * 16 + (lane >> 4) * 4 + r;
                size_t idx = (size_t)row * 512 + col;
                float vi = sigm(acc_i[m][n][r] + bi);
                float vu = tanh_pf(acc_u[m][n][r] + bu);
                Pq[idx] = f2bf(vi * vu);
                Oq[idx] = f2bf(sigm(acc_o[m][n][r] + bo));
                Fq[idx] = f2bf(acc_f[m][n][r] + bf);
            }
        }
    }
}

// ---------------- f-einsum + combine kernel ----------------
// BM=64 child rows (8 nodes), BN=512 (full width -> child_h read ONCE).
// 8 waves (1x8), wave tile 64x64. Fragment-order LDS, double-buffered:
// waves 0-3 convert A (fp32->bf16, ds_write), waves 4-7 issue B gl16.
__global__ __launch_bounds__(512, 2) void k_fc(
    const float* __restrict__ ch,            // child_h [65536][512] fp32
    const float* __restrict__ cc,            // child_c
    const unsigned short* __restrict__ ufT,  // Uf^T bf16 [512][512]
    const float* __restrict__ bUf,
    const unsigned short* __restrict__ Pq,
    const unsigned short* __restrict__ Oq,
    const unsigned short* __restrict__ Fq,
    float* __restrict__ out)                 // [2][8192][512]
{
    // per buffer: A = 4 subtiles (2048 sh), B = 32 subtiles (16384 sh) -> 36KB
    __shared__ unsigned short lds[2][18432];
    const int t = threadIdx.x, lane = t & 63, wid = t >> 6;
    const int wc = wid;
    const int r0c = blockIdx.x * 64;            // child-row base

    f32x4 acc[4][4] = {};
    const int frow = lane & 15, fk = (lane >> 4) * 8;

    auto stage = [&](unsigned short* buf, int kq) {
        if (t < 256) {
            // A: thread t fills fragment slot t (16B): row 16*(t>>6)+(t&15), k-slot (t>>4)&3
            int row = 16 * (t >> 6) + (t & 15), ks = (t >> 4) & 3;
            const float* src = &ch[(size_t)(r0c + row) * 512 + kq + ks * 8];
            float4 v0 = *(const float4*)src;
            float4 v1 = *(const float4*)(src + 4);
            uint4 o;
            o.x = (unsigned)f2bf(v0.x) | ((unsigned)f2bf(v0.y) << 16);
            o.y = (unsigned)f2bf(v0.z) | ((unsigned)f2bf(v0.w) << 16);
            o.z = (unsigned)f2bf(v1.x) | ((unsigned)f2bf(v1.y) << 16);
            o.w = (unsigned)f2bf(v1.z) | ((unsigned)f2bf(v1.w) << 16);
            *(uint4*)&buf[t * 8] = o;
        } else {
            int w = wid - 4;
#pragma unroll
            for (int j = 0; j < 8; ++j) {
                int s2 = w * 8 + j;
                gl16(&ufT[(size_t)(s2 * 16 + frow) * 512 + kq + fk], &buf[2048 + s2 * 512]);
            }
        }
    };

    stage(lds[0], 0);

#pragma unroll 1
    for (int kq = 0; kq < 512; kq += 32) {
        unsigned short* cur = lds[(kq >> 5) & 1];
        unsigned short* nxt = lds[((kq >> 5) & 1) ^ 1];
        __syncthreads();
        if (kq < 480) stage(nxt, kq + 32);
        short8 af[4], bfr[4];
#pragma unroll
        for (int m = 0; m < 4; ++m) af[m] = *(const short8*)&cur[m * 512 + lane * 8];
#pragma unroll
        for (int n = 0; n < 4; ++n) bfr[n] = *(const short8*)&cur[2048 + (wc * 4 + n) * 512 + lane * 8];
#pragma unroll
        for (int m = 0; m < 4; ++m)
#pragma unroll
            for (int n = 0; n < 4; ++n)
                acc[m][n] = __builtin_amdgcn_mfma_f32_16x16x32_bf16(af[m], bfr[n], acc[m][n], 0, 0, 0);
    }

    // epilogue: in-register per-node reduce over 8 children
    const int g = lane >> 4;
    float bUfv[4];
#pragma unroll
    for (int n = 0; n < 4; ++n) bUfv[n] = bUf[wc * 64 + n * 16 + (lane & 15)];

#pragma unroll
    for (int m = 0; m < 4; ++m) {
        int node = (r0c >> 3) + 2 * m + (g >> 1);
#pragma unroll
        for (int n = 0; n < 4; ++n) {
            int col = wc * 64 + n * 16 + (lane & 15);
            size_t nidx = (size_t)node * 512 + col;
            float xf = bf2f(Fq[nidx]) + bUfv[n];
            float fcs = 0.f;
#pragma unroll
            for (int r = 0; r < 4; ++r) {
                int R = r0c + m * 16 + g * 4 + r;
                float pre = acc[m][n][r] + xf;
                fcs += sigm(pre) * cc[(size_t)R * 512 + col];
            }
            fcs += __shfl_xor(fcs, 16);
            if ((g & 1) == 0) {   // lanes g=0 (node 2m), g=2 (node 2m+1) write
                float cv = bf2f(Pq[nidx]) + fcs;
                out[nidx] = bf2f(Oq[nidx]) * tanh_pf(cv);
                out[(size_t)NN * HH + nidx] = cv;
            }
        }
    }
}

// ---------------- launch ----------------
extern "C" void kernel_launch(void* const* d_in, const int* in_sizes, int n_in,
                              void* d_out, int out_size, void* d_ws, size_t ws_size,
                              hipStream_t stream) {
    const float* x   = (const float*)d_in[0];
    const float* ch  = (const float*)d_in[1];
    const float* cc  = (const float*)d_in[2];
    const float* Wi  = (const float*)d_in[3];  const float* bWi = (const float*)d_in[4];
    const float* Ui  = (const float*)d_in[5];  const float* bUi = (const float*)d_in[6];
    const float* Wf  = (const float*)d_in[7];  const float* bWf = (const float*)d_in[8];
    const float* Uf  = (const float*)d_in[9];  const float* bUf = (const float*)d_in[10];
    const float* Wo  = (const float*)d_in[11]; const float* bWo = (const float*)d_in[12];
    const float* Uo  = (const float*)d_in[13]; const float* bUo = (const float*)d_in[14];
    const float* Wu  = (const float*)d_in[15]; const float* bWu = (const float*)d_in[16];
    const float* Uu  = (const float*)d_in[17]; const float* bUu = (const float*)d_in[18];
    float* out = (float*)d_out;

    unsigned short* xb  = (unsigned short*)d_ws;                 // 8192*512
    unsigned short* hsb = xb  + (size_t)NN * HH;                 // 8192*512
    unsigned short* wT  = hsb + (size_t)NN * HH;                 // 8*512*512
    unsigned short* Pq  = wT  + (size_t)8 * 262144;
    unsigned short* Oq  = Pq  + (size_t)NN * HH;
    unsigned short* Fq  = Oq  + (size_t)NN * HH;

    k_cvt<<<(NN * HH / 8) / 256, 256, 0, stream>>>(x, xb);
    k_hsum<<<(NN * 128) / 256, 256, 0, stream>>>(ch, hsb);
    P8 wp;  // order: Wi,Wf,Wo,Wu, Ui,Uo,Uu, Uf
    wp.p[0] = Wi; wp.p[1] = Wf; wp.p[2] = Wo; wp.p[3] = Wu;
    wp.p[4] = Ui; wp.p[5] = Uo; wp.p[6] = Uu; wp.p[7] = Uf;
    k_transpose_w<<<dim3(16, 16, 8), dim3(32, 8), 0, stream>>>(wp, wT);
    k_gates<<<dim3(512), 256, 0, stream>>>(xb, hsb, wT,
                                           bWi, bUi, bWf, bWo, bUo, bWu, bUu,
                                           Pq, Oq, Fq);
    k_fc<<<dim3(1024), 512, 0, stream>>>(ch, cc, wT + (size_t)7 * 262144, bUf,
                                         Pq, Oq, Fq, out);
}